// Round 7
// baseline (126.917 us; speedup 1.0000x reference)
//
#include <hip/hip_runtime.h>
#include <cfloat>
#include <cmath>

#define DIM 64
#define TT 2048
#define NTOT 65536
#define KE 1024

typedef _Float16 f16x8 __attribute__((ext_vector_type(8)));
typedef _Float16 f16x4 __attribute__((ext_vector_type(4)));
typedef float    f32x4 __attribute__((ext_vector_type(4)));

// ws layout (bytes):
//   planes [0, 262144)      : fp16 hi plane (131072 B) + fp16 lo plane (131072 B)
//   e2     [262144, 266240) : 1024 f32
// plane vector layout (B-fragment-ready, verified R5/R6): f16x8 index
//   ((g*2+k)*64 + l) for group g (16 codes), kstep k, lane l=q*16+ln holding
//   embed_plane[c=g*16+ln][j=k*32+q*8 .. +7].
#define WS_NEED 266240

// ============================ fast path ====================================
__global__ __launch_bounds__(256) void prep_kernel(
    const float* __restrict__ embed,
    _Float16* __restrict__ planes,
    float* __restrict__ e2g,
    float* __restrict__ counts,        // out_avg region  (zeroed here)
    float* __restrict__ distsum)       // out_commit slot (zeroed here)
{
    const int gidx = blockIdx.x * 256 + threadIdx.x;   // 8192 threads
    const int g  = gidx >> 7;
    const int k  = (gidx >> 6) & 1;
    const int l  = gidx & 63;
    const int q  = l >> 4;
    const int ln = l & 15;
    const int c  = g * 16 + ln;
    const int jb = k * 32 + q * 8;

    const float4 v0 = *(const float4*)(embed + (size_t)c * DIM + jb);
    const float4 v1 = *(const float4*)(embed + (size_t)c * DIM + jb + 4);
    const float xf[8] = {v0.x, v0.y, v0.z, v0.w, v1.x, v1.y, v1.z, v1.w};
    f16x8 h1, h2;
    #pragma unroll
    for (int e = 0; e < 8; ++e) {
        const _Float16 a = (_Float16)xf[e];
        h1[e] = a;
        h2[e] = (_Float16)(xf[e] - (float)a);   // exact residual
    }
    const int off = ((g * 2 + k) * 64 + l) * 8;
    *(f16x8*)(planes + off)         = h1;
    *(f16x8*)(planes + 65536 + off) = h2;

    if (gidx < KE) {
        const float4* rp = (const float4*)(embed + (size_t)gidx * DIM);
        float s = 0.f;
        #pragma unroll
        for (int i = 0; i < 16; ++i) {
            const float4 v = rp[i];
            s += v.x * v.x + v.y * v.y + v.z * v.z + v.w * v.w;
        }
        e2g[gidx]    = s;
        counts[gidx] = 0.f;
        if (gidx == 0) distsum[0] = 0.f;
    }
}

// Fused argmin + gather (R6 structure) with the VGPR cap LIFTED.
// R0-R6 post-mortem: every "pipelined" variant ran under launch_bounds
// giving a 64-VGPR cap (VGPR_Count 56-60) -> A-frags(32) + in-flight
// B-frags(16) + state(~30) cannot fit, so the scheduler was FORCED to
// issue+drain loads inside each iteration (exposed L2 latency ~ 54us of
// stall in R6). Grid 512 already limits residency to 2 blocks/CU, so
// __launch_bounds__(512,2) raises the cap to 128 VGPR at zero occupancy
// cost, and a source-level distance-1 B prefetch can survive allocation.
// Telltale: VGPR_Count should jump to ~90-120; if it stays ~56 the cap
// wasn't binding and this theory is falsified.
// Numerics identical to verified R6: same planes, same 6-MFMA order
// (lo*hi, hi*lo, hi*hi, small terms first), strict < + ascending ties.
__global__ __launch_bounds__(512, 2) void argmin_fused(
    const float* __restrict__ x,       // [B][D][T]
    const f16x8* __restrict__ P,       // ws planes (hi at +0, lo at +131072 B)
    const float* __restrict__ e2g,     // ws e2
    const float* __restrict__ embed,
    float* __restrict__ out_q,
    float* __restrict__ out_idx,
    float* __restrict__ counts,
    float* __restrict__ distsum)
{
    __shared__ float e2s[1024];
    __shared__ float rs[2][128];       // per-K-half candidates
    __shared__ int   ri[2][128];
    __shared__ float x2s[128];
    __shared__ int   ibest[128];

    const int tid = threadIdx.x;       // 0..511
    const int l   = tid & 63;
    const int w   = tid >> 6;          // 0..7
    const int wq  = w & 3;             // t-quarter within block
    const int kq  = w >> 2;            // K-half
    const int q   = l >> 4;
    const int ln  = l & 15;
    const int bid = blockIdx.x;        // 512 blocks = 32 b x 16 t-tiles
    const int b   = bid >> 4;
    const int t0  = (bid & 15) << 7;   // 128 t per block

    if (tid < 256)
        *(float4*)&e2s[tid * 4] = *(const float4*)(e2g + tid * 4);

    // ---- A fragments: fp16 split in registers (layout verified R5/R6) ----
    // t = t0 + wq*32 + m*16 + ln, j = k*32 + q*8 + jj
    f16x8 af[2][2][2];                 // [plane][m][k]
    float x2p[2] = {0.f, 0.f};
    #pragma unroll
    for (int m = 0; m < 2; ++m)
        #pragma unroll
        for (int k = 0; k < 2; ++k)
            #pragma unroll
            for (int jj = 0; jj < 8; ++jj) {
                const int j = k * 32 + q * 8 + jj;
                const float xf = x[(size_t)(b * DIM + j) * TT + t0 + wq * 32 + m * 16 + ln];
                const _Float16 h1 = (_Float16)xf;
                af[0][m][k][jj] = h1;
                af[1][m][k][jj] = (_Float16)(xf - (float)h1);
                x2p[m] = fmaf(xf, xf, x2p[m]);
            }
    // full ||x_t||^2: sum the 4 q-quarters (lanes with same ln)
    #pragma unroll
    for (int m = 0; m < 2; ++m) {
        x2p[m] += __shfl_xor(x2p[m], 16);
        x2p[m] += __shfl_xor(x2p[m], 32);
    }
    if (kq == 0 && q == 0) {
        x2s[wq * 32 + ln]      = x2p[0];
        x2s[wq * 32 + 16 + ln] = x2p[1];
    }
    __syncthreads();                   // e2s, x2s ready (only pre-loop barrier)

    float bs[2][4];
    int   bi_[2][4];
    #pragma unroll
    for (int m = 0; m < 2; ++m)
        #pragma unroll
        for (int r = 0; r < 4; ++r) { bs[m][r] = FLT_MAX; bi_[m][r] = 0; }

    // ---- hot loop: 32 groups of 16 codes from this wave's K-half ----
    // Distance-1 register prefetch: next group's 4 B-fragments stay in
    // flight across the current group's 12 MFMAs (needs >64 VGPR budget).
    // Tail prefetch gl=32: kq=0 reads lo-plane start, kq=1 reads e2 region
    // (byte offsets < 266240) -> in-bounds of ws, values unused.
    const f16x8* base = P + l + kq * 4096;
    f16x8 c0 = base[0];                // hi plane, k0
    f16x8 c1 = base[64];               // hi plane, k1
    f16x8 c2 = base[8192];             // lo plane, k0
    f16x8 c3 = base[8192 + 64];        // lo plane, k1
    #pragma unroll 1
    for (int gl = 0; gl < 32; ++gl) {
        const f16x8* np = base + (gl + 1) * 128;
        f16x8 n0 = np[0];
        f16x8 n1 = np[64];
        f16x8 n2 = np[8192];
        f16x8 n3 = np[8192 + 64];
        const int   cgl  = kq * 512 + gl * 16 + ln;
        const float e2c  = e2s[cgl];
        #pragma unroll
        for (int m = 0; m < 2; ++m) {
            f32x4 C = {0.f, 0.f, 0.f, 0.f};
            // 6-MFMA split (verified R5/R6): lo*hi, hi*lo, hi*hi, small first
            C = __builtin_amdgcn_mfma_f32_16x16x32_f16(af[1][m][0], c0, C, 0, 0, 0);
            C = __builtin_amdgcn_mfma_f32_16x16x32_f16(af[1][m][1], c1, C, 0, 0, 0);
            C = __builtin_amdgcn_mfma_f32_16x16x32_f16(af[0][m][0], c2, C, 0, 0, 0);
            C = __builtin_amdgcn_mfma_f32_16x16x32_f16(af[0][m][1], c3, C, 0, 0, 0);
            C = __builtin_amdgcn_mfma_f32_16x16x32_f16(af[0][m][0], c0, C, 0, 0, 0);
            C = __builtin_amdgcn_mfma_f32_16x16x32_f16(af[0][m][1], c1, C, 0, 0, 0);
            #pragma unroll
            for (int r = 0; r < 4; ++r) {
                const float s = fmaf(-2.f, C[r], e2c);
                // strict < + ascending c keeps lowest index on ties
                if (s < bs[m][r]) { bs[m][r] = s; bi_[m][r] = cgl; }
            }
        }
        c0 = n0; c1 = n1; c2 = n2; c3 = n3;
    }

    // ---- per-wave reduce over the 16 code-columns -> LDS candidates ----
    #pragma unroll
    for (int m = 0; m < 2; ++m)
        #pragma unroll
        for (int r = 0; r < 4; ++r) {
            float s = bs[m][r]; int i = bi_[m][r];
            #pragma unroll
            for (int mask = 1; mask < 16; mask <<= 1) {
                const float s2 = __shfl_xor(s, mask);
                const int   i2 = __shfl_xor(i, mask);
                if (s2 < s || (s2 == s && i2 < i)) { s = s2; i = i2; }
            }
            if (ln == 0) {
                const int t_loc = wq * 32 + m * 16 + q * 4 + r;  // C-row map
                rs[kq][t_loc] = s;
                ri[kq][t_loc] = i;
            }
        }
    __syncthreads();

    // ---- cross-K-half reduce; kq0 indices < kq1: strict < keeps ties ----
    if (tid < 128) {
        float s = rs[0][tid]; int i = ri[0][tid];
        const float s1 = rs[1][tid];
        if (s1 < s) { s = s1; i = ri[1][tid]; }
        ibest[tid] = i;
        out_idx[bid * 128 + tid] = (float)i;     // == b*TT + t0 + tid
        atomicAdd(&counts[i], 1.0f);
        float md = x2s[tid] + s;                 // ||x||^2 + e^2 - 2 x.e
        #pragma unroll
        for (int off = 1; off < 64; off <<= 1) md += __shfl_xor(md, off);
        if (l == 0) atomicAdd(distsum, md);      // 2 atomics per block
    }
    __syncthreads();

    // ---- gather: out_q[b][j][t0+tt] = embed[ibest[tt]][j] (embed L2-hot) ---
    #pragma unroll
    for (int p = 0; p < 16; ++p) {
        const int f  = p * 512 + tid;
        const int j  = f >> 7;
        const int tt = f & 127;
        out_q[(size_t)(b * DIM + j) * TT + t0 + tt] =
            embed[(size_t)ibest[tt] * DIM + j];
    }
}

// ======================= fallback path (Round-5, passed) ====================
#define EP_ROW   72
#define EP_PLANE 4608
#define SMEM_BYTES (36864 + 4096 + 512 + 512 + 16)

__global__ __launch_bounds__(256, 2) void argmin_fb(
    const float* __restrict__ x, const float* __restrict__ embed,
    float* __restrict__ out_q, float* __restrict__ out_idx,
    float* __restrict__ counts, float* __restrict__ distsum)
{
    __shared__ __align__(16) char smem[SMEM_BYTES];
    _Float16* ep  = (_Float16*)smem;
    float* e2s    = (float*)(smem + 36864);
    float* x2s    = (float*)(smem + 36864 + 4096);
    int*   ibest  = (int*)  (smem + 36864 + 4608);
    float* mdsum  = (float*)(smem + 36864 + 5120);

    const int tid = threadIdx.x;
    const int l   = tid & 63;
    const int w   = tid >> 6;
    const int q   = l >> 4;
    const int ln  = l & 15;
    const int bid = blockIdx.x;
    const int b   = bid >> 4;
    const int t0  = (bid & 15) << 7;

    if (tid == 0) mdsum[0] = 0.f;
    #pragma unroll
    for (int pass = 0; pass < 4; ++pass) {
        const int c = pass * 256 + tid;
        const float4* rp = (const float4*)(embed + (size_t)c * DIM);
        float s = 0.f;
        #pragma unroll
        for (int i = 0; i < 16; ++i) {
            const float4 v = rp[i];
            s += v.x * v.x + v.y * v.y + v.z * v.z + v.w * v.w;
        }
        e2s[c] = s;
    }
    f16x8 af[2][2][2];
    float x2p[2] = {0.f, 0.f};
    #pragma unroll
    for (int m = 0; m < 2; ++m)
        #pragma unroll
        for (int k = 0; k < 2; ++k)
            #pragma unroll
            for (int jj = 0; jj < 8; ++jj) {
                const int j = k * 32 + q * 8 + jj;
                const float xf = x[(size_t)(b * DIM + j) * TT + t0 + w * 32 + m * 16 + ln];
                const _Float16 h1 = (_Float16)xf;
                af[0][m][k][jj] = h1;
                af[1][m][k][jj] = (_Float16)(xf - (float)h1);
                x2p[m] = fmaf(xf, xf, x2p[m]);
            }
    #pragma unroll
    for (int m = 0; m < 2; ++m) {
        x2p[m] += __shfl_xor(x2p[m], 16);
        x2p[m] += __shfl_xor(x2p[m], 32);
    }
    if (q == 0) { x2s[w * 32 + ln] = x2p[0]; x2s[w * 32 + 16 + ln] = x2p[1]; }
    {
        #pragma unroll
        for (int pass = 0; pass < 4; ++pass) {
            const int c_loc = (tid >> 4) + pass * 16;
            const int j4    = (tid & 15) * 4;
            const float4 v = *(const float4*)(embed + (size_t)c_loc * DIM + j4);
            f16x4 h1, h2;
            h1[0] = (_Float16)v.x; h2[0] = (_Float16)(v.x - (float)h1[0]);
            h1[1] = (_Float16)v.y; h2[1] = (_Float16)(v.y - (float)h1[1]);
            h1[2] = (_Float16)v.z; h2[2] = (_Float16)(v.z - (float)h1[2]);
            h1[3] = (_Float16)v.w; h2[3] = (_Float16)(v.w - (float)h1[3]);
            *(f16x4*)(ep + c_loc * EP_ROW + j4)            = h1;
            *(f16x4*)(ep + EP_PLANE + c_loc * EP_ROW + j4) = h2;
        }
    }
    __syncthreads();
    float bs[2][4]; int bi[2][4];
    #pragma unroll
    for (int m = 0; m < 2; ++m)
        #pragma unroll
        for (int r = 0; r < 4; ++r) { bs[m][r] = FLT_MAX; bi[m][r] = 0; }
    for (int kc = 0; kc < 16; ++kc) {
        const int cur = kc & 1, nxt = cur ^ 1;
        float4 ev[4];
        if (kc < 15)
            #pragma unroll
            for (int pass = 0; pass < 4; ++pass) {
                const int c_loc = (tid >> 4) + pass * 16;
                const int j4    = (tid & 15) * 4;
                ev[pass] = *(const float4*)(embed + (size_t)((kc + 1) * 64 + c_loc) * DIM + j4);
            }
        const _Float16* p1 = ep + cur * 2 * EP_PLANE;
        const _Float16* p2 = p1 + EP_PLANE;
        #pragma unroll
        for (int n = 0; n < 4; ++n) {
            const int coff = (n * 16 + ln) * EP_ROW + q * 8;
            const f16x8 b1k0 = *(const f16x8*)(p1 + coff);
            const f16x8 b1k1 = *(const f16x8*)(p1 + coff + 32);
            const f16x8 b2k0 = *(const f16x8*)(p2 + coff);
            const f16x8 b2k1 = *(const f16x8*)(p2 + coff + 32);
            const int   c_lane = kc * 64 + n * 16 + ln;
            const float e2c    = e2s[c_lane];
            #pragma unroll
            for (int m = 0; m < 2; ++m) {
                f32x4 C = {0.f, 0.f, 0.f, 0.f};
                C = __builtin_amdgcn_mfma_f32_16x16x32_f16(af[1][m][0], b2k0, C, 0, 0, 0);
                C = __builtin_amdgcn_mfma_f32_16x16x32_f16(af[1][m][1], b2k1, C, 0, 0, 0);
                C = __builtin_amdgcn_mfma_f32_16x16x32_f16(af[1][m][0], b1k0, C, 0, 0, 0);
                C = __builtin_amdgcn_mfma_f32_16x16x32_f16(af[1][m][1], b1k1, C, 0, 0, 0);
                C = __builtin_amdgcn_mfma_f32_16x16x32_f16(af[0][m][0], b2k0, C, 0, 0, 0);
                C = __builtin_amdgcn_mfma_f32_16x16x32_f16(af[0][m][1], b2k1, C, 0, 0, 0);
                C = __builtin_amdgcn_mfma_f32_16x16x32_f16(af[0][m][0], b1k0, C, 0, 0, 0);
                C = __builtin_amdgcn_mfma_f32_16x16x32_f16(af[0][m][1], b1k1, C, 0, 0, 0);
                #pragma unroll
                for (int r = 0; r < 4; ++r) {
                    const float s = fmaf(-2.f, C[r], e2c);
                    if (s < bs[m][r]) { bs[m][r] = s; bi[m][r] = c_lane; }
                }
            }
        }
        if (kc < 15) {
            _Float16* w1 = ep + nxt * 2 * EP_PLANE;
            _Float16* w2 = w1 + EP_PLANE;
            #pragma unroll
            for (int pass = 0; pass < 4; ++pass) {
                const int c_loc = (tid >> 4) + pass * 16;
                const int j4    = (tid & 15) * 4;
                const float4 v = ev[pass];
                f16x4 h1, h2;
                h1[0] = (_Float16)v.x; h2[0] = (_Float16)(v.x - (float)h1[0]);
                h1[1] = (_Float16)v.y; h2[1] = (_Float16)(v.y - (float)h1[1]);
                h1[2] = (_Float16)v.z; h2[2] = (_Float16)(v.z - (float)h1[2]);
                h1[3] = (_Float16)v.w; h2[3] = (_Float16)(v.w - (float)h1[3]);
                *(f16x4*)(w1 + c_loc * EP_ROW + j4) = h1;
                *(f16x4*)(w2 + c_loc * EP_ROW + j4) = h2;
            }
        }
        __syncthreads();
    }
    float mdloc = 0.f;
    #pragma unroll
    for (int m = 0; m < 2; ++m)
        #pragma unroll
        for (int r = 0; r < 4; ++r) {
            float s = bs[m][r]; int i = bi[m][r];
            #pragma unroll
            for (int mask = 1; mask < 16; mask <<= 1) {
                const float s2 = __shfl_xor(s, mask);
                const int   i2 = __shfl_xor(i, mask);
                if (s2 < s || (s2 == s && i2 < i)) { s = s2; i = i2; }
            }
            if (ln == 0) {
                const int t_loc = w * 32 + m * 16 + q * 4 + r;
                ibest[t_loc] = i;
                out_idx[b * TT + t0 + t_loc] = (float)i;
                atomicAdd(&counts[i], 1.0f);
                mdloc += x2s[t_loc] + s;
            }
        }
    if (ln == 0) atomicAdd(mdsum, mdloc);
    __syncthreads();
    if (tid == 0) atomicAdd(distsum, mdsum[0]);
    #pragma unroll
    for (int p = 0; p < 32; ++p) {
        const int f  = p * 256 + tid;
        const int j  = f >> 7;
        const int tt = f & 127;
        out_q[(size_t)(b * DIM + j) * TT + t0 + tt] =
            embed[(size_t)ibest[tt] * DIM + j];
    }
}

// finalize: in-place counts->avg_probs, perplexity, usage, commitment
__global__ __launch_bounds__(1024) void finalize_kernel(
    float* __restrict__ avg, float* __restrict__ commit_slot,
    float* __restrict__ out_perp, float* __restrict__ out_usage)
{
    __shared__ float s_ent[1024];
    __shared__ float s_use[1024];
    const int k = threadIdx.x;
    const float p = avg[k] * (1.0f / (float)NTOT);
    avg[k] = p;
    s_ent[k] = p * logf(p + 1e-10f);
    s_use[k] = p * logf(p * 1024.f + 1e-10f);
    __syncthreads();
    for (int off = 512; off > 0; off >>= 1) {
        if (k < off) { s_ent[k] += s_ent[k + off]; s_use[k] += s_use[k + off]; }
        __syncthreads();
    }
    if (k == 0) {
        const float ds = commit_slot[0];
        *out_perp      = expf(-s_ent[0]);
        *out_usage     = s_use[0];
        commit_slot[0] = 0.25f * ds * (1.0f / ((float)NTOT * (float)DIM));
    }
}

extern "C" void kernel_launch(void* const* d_in, const int* in_sizes, int n_in,
                              void* d_out, int out_size, void* d_ws, size_t ws_size,
                              hipStream_t stream) {
    const float* x     = (const float*)d_in[0];
    const float* embed = (const float*)d_in[1];

    float* out        = (float*)d_out;
    float* out_q      = out;             // 4194304
    float* out_commit = out + 4194304;   // distsum accumulator first
    float* out_perp   = out + 4194305;
    float* out_avg    = out + 4194306;   // counts accumulator first
    float* out_idx    = out + 4195330;
    // usage at out + 4260866

    if (ws_size >= WS_NEED) {
        _Float16* planes = (_Float16*)d_ws;
        float*    e2g    = (float*)((char*)d_ws + 262144);
        prep_kernel<<<32, 256, 0, stream>>>(embed, planes, e2g, out_avg, out_commit);
        argmin_fused<<<512, 512, 0, stream>>>(x, (const f16x8*)planes, e2g, embed,
                                              out_q, out_idx, out_avg, out_commit);
    } else {
        hipMemsetAsync(out_commit, 0, 1026 * sizeof(float), stream);
        argmin_fb<<<512, 256, 0, stream>>>(x, embed, out_q, out_idx, out_avg, out_commit);
    }
    finalize_kernel<<<1, 1024, 0, stream>>>(out_avg, out_commit, out_perp, out + 4260866);
}